// Round 2
// baseline (670.905 us; speedup 1.0000x reference)
//
#include <hip/hip_runtime.h>

#define I_DIM 128
#define H_DIM 64
#define BATCH 8
#define SEQ   4096
#define NBIN  (SEQ/2 + 1)   // 2049

// Module-scope device scratch: allocated at .so load time, graph-capture safe,
// no dependence on ws_size (round-1 post-timing divergence was consistent with
// an OOB write into an undersized d_ws racing adjacent allocations).
__device__ float2 g_Hh[I_DIM * NBIN];   // K_hat, ~2.1 MB
__device__ float  g_Kt[SEQ * I_DIM];    // K transposed [s][i], 2 MB

// ---------------------------------------------------------------------------
// Kernel 1: K_hat[i,k] = c_k * (k00 - k01*(1+k11)*k10), k = 0..L/2
// One thread per (i, k); loop over hidden dim H=64.
// ---------------------------------------------------------------------------
__global__ void khat_kernel(const float* __restrict__ Bm,
                            const float* __restrict__ Cm,
                            const float* __restrict__ Lm,
                            const float* __restrict__ Pm,
                            const float* __restrict__ Qm) {
    int k = blockIdx.x * blockDim.x + threadIdx.x;
    int i = blockIdx.y;
    if (k >= NBIN) return;

    float theta = (float)(6.283185307179586 / (double)SEQ) * (float)k;
    float sn, cs;
    sincosf(theta, &sn, &cs);

    // g = (2/dt)*(1-omega)/(1+omega) = 20*(...);  c = 2/(1+omega)
    float tr = 1.0f - cs, ti = -sn;
    float br = 1.0f + cs, bi = sn;
    float den = br * br + bi * bi;          // > 0 even at k=L/2 in f32
    float idn = 1.0f / den;
    float gr = 20.0f * (tr * br + ti * bi) * idn;
    float gi = 20.0f * (ti * br - tr * bi) * idn;
    float cr = 2.0f * br * idn;
    float ci = -2.0f * bi * idn;

    const float* Brow = Bm + i * H_DIM;
    const float* Crow = Cm + i * H_DIM;
    const float* Lrow = Lm + i * H_DIM;   // Lambda is [I,1,H] -> flat [I,H]
    const float* Prow = Pm + i * H_DIM;
    const float* Qrow = Qm + i * H_DIM;

    float k00r = 0.f, k00i = 0.f, k01r = 0.f, k01i = 0.f;
    float k10r = 0.f, k10i = 0.f, k11r = 0.f, k11i = 0.f;

#pragma unroll 8
    for (int h = 0; h < H_DIM; ++h) {
        float lam = Lrow[h];
        float dr = gr - lam;
        float di = gi;
        float im = 1.0f / (dr * dr + di * di);
        float ivr = dr * im;
        float ivi = -di * im;
        float bv = Brow[h], cv = Crow[h], pv = Prow[h], qv = Qrow[h];
        float cb = cv * bv;   // conj(C)*B with real C
        float cp = cv * pv;
        float qb = qv * bv;
        float qp = qv * pv;
        k00r += cb * ivr; k00i += cb * ivi;
        k01r += cp * ivr; k01i += cp * ivi;
        k10r += qb * ivr; k10i += qb * ivi;
        k11r += qp * ivr; k11i += qp * ivi;
    }

    float t1r = 1.0f + k11r, t1i = k11i;
    float t2r = k01r * t1r - k01i * t1i;
    float t2i = k01r * t1i + k01i * t1r;
    float t3r = t2r * k10r - t2i * k10i;
    float t3i = t2r * k10i + t2i * k10r;
    float nr = k00r - t3r, ni = k00i - t3i;
    float Hr = cr * nr - ci * ni;
    float Hi = cr * ni + ci * nr;
    g_Hh[(size_t)i * NBIN + k] = make_float2(Hr, Hi);
}

// ---------------------------------------------------------------------------
// Kernel 2: K[i,s] = irfft(K_hat)[s] via Hermitian DFT. Twiddle rotation
// recurrence, re-synchronized every 256 steps from the EXACT integer phase
// ((k0*s) & (L-1)) to kill drift. Output transposed: Kt[s*I + i].
// ---------------------------------------------------------------------------
__global__ void irfft_kernel() {
    int s = blockIdx.x * blockDim.x + threadIdx.x;   // 0..4095
    int i = blockIdx.y;
    const float2* Hrow = g_Hh + (size_t)i * NBIN;

    const float step = (float)(6.283185307179586 / (double)SEQ);
    float Wi, Wr;
    sincosf(step * (float)s, &Wi, &Wr);      // W = e^{i*2*pi*s/L}

    float2 h0 = Hrow[0];
    float2 hN = Hrow[SEQ / 2];
    float acc = h0.x + ((s & 1) ? -hN.x : hN.x);

    for (int k0 = 0; k0 < SEQ / 2; k0 += 256) {
        // exact phase at k0: (k0*s) mod L, integer arithmetic
        int m = (k0 * s) & (SEQ - 1);
        float Tr, Ti;
        sincosf(step * (float)m, &Ti, &Tr);  // T = W^{k0}
        int kbeg = (k0 == 0) ? 1 : k0;       // skip k=0 (handled above)
        if (k0 == 0) {                       // advance T from k0 to k=1
            float nTr = Tr * Wr - Ti * Wi;
            float nTi = Tr * Wi + Ti * Wr;
            Tr = nTr; Ti = nTi;
        }
#pragma unroll 4
        for (int k = kbeg; k < k0 + 256; ++k) {
            float2 h = Hrow[k];
            acc += 2.0f * (h.x * Tr - h.y * Ti);
            float nTr = Tr * Wr - Ti * Wi;
            float nTi = Tr * Wi + Ti * Wr;
            Tr = nTr; Ti = nTi;
        }
    }
    g_Kt[(size_t)s * I_DIM + i] = acc * (1.0f / (float)SEQ);
}

// ---------------------------------------------------------------------------
// Kernel 3: causal depthwise conv
//   y[b,t,i] = sum_{u=0}^{t} x[b,u,i] * K[i, t-u]
// Block: 128 threads (lane = i), computes 16 consecutive t for one b.
// K window kept in a 16-deep circular register buffer with static indices.
// ---------------------------------------------------------------------------
__global__ __launch_bounds__(128) void conv_kernel(const float* __restrict__ x,
                                                   float* __restrict__ y) {
    const int i  = threadIdx.x;
    const int t0 = blockIdx.x * 16;
    const int b  = blockIdx.y;

    const float* xb = x + ((size_t)b * SEQ) * I_DIM + i;

    float acc[16];
    float kw[16];
#pragma unroll
    for (int j = 0; j < 16; ++j) {
        acc[j] = 0.0f;
        kw[j] = g_Kt[(size_t)(t0 + j) * I_DIM + i];  // kw[j] = K[t0+j-ub], ub=0
    }

    // bulk: u = 0 .. t0-1 (all 16 accumulators active)
    for (int ub = 0; ub < t0; ub += 16) {
#pragma unroll
        for (int uu = 0; uu < 16; ++uu) {
            float xv = xb[(size_t)(ub + uu) * I_DIM];
#pragma unroll
            for (int r = 0; r < 16; ++r)
                acc[r] += xv * kw[(r - uu + 16) & 15];
            // refill: newest needed K index is t0 - (ub+uu) - 1
            kw[(15 - uu) & 15] = g_Kt[(size_t)(t0 - ub - uu - 1) * I_DIM + i];
        }
    }

    // tail: u = t0 .. t0+15, acc[r] active for r >= uu; kw[j] == K[j] here
#pragma unroll
    for (int uu = 0; uu < 16; ++uu) {
        float xv = xb[(size_t)(t0 + uu) * I_DIM];
#pragma unroll
        for (int r = uu; r < 16; ++r)
            acc[r] += xv * kw[(r - uu) & 15];
    }

    float* yb = y + ((size_t)b * SEQ + t0) * I_DIM + i;
#pragma unroll
    for (int r = 0; r < 16; ++r)
        yb[(size_t)r * I_DIM] = acc[r];
}

// ---------------------------------------------------------------------------
extern "C" void kernel_launch(void* const* d_in, const int* in_sizes, int n_in,
                              void* d_out, int out_size, void* d_ws, size_t ws_size,
                              hipStream_t stream) {
    const float* x  = (const float*)d_in[0];
    const float* Bm = (const float*)d_in[1];
    const float* Cm = (const float*)d_in[2];
    const float* Lm = (const float*)d_in[3];
    const float* Pm = (const float*)d_in[4];
    const float* Qm = (const float*)d_in[5];
    float* out = (float*)d_out;

    khat_kernel<<<dim3((NBIN + 255) / 256, I_DIM), 256, 0, stream>>>(Bm, Cm, Lm, Pm, Qm);
    irfft_kernel<<<dim3(SEQ / 256, I_DIM), 256, 0, stream>>>();
    conv_kernel<<<dim3(SEQ / 16, BATCH), 128, 0, stream>>>(x, out);
}

// Round 3
// 119.007 us; speedup vs baseline: 5.6375x; 5.6375x over previous
//
#include <hip/hip_runtime.h>

#define I_DIM 128
#define H_DIM 64
#define BATCH 8
#define SEQ   4096
#define NBIN  (SEQ/2 + 1)     // 2049 bins of the 4096-rfft (K_hat)
#define NBIN2 (SEQ + 1)       // 4097 bins of the 8192-rfft (Kf)

// LDS address swizzle (involution): spreads early-stage Stockham writes
// across banks while keeping consecutive runs consecutive-ish.
#define SZ(a) ((a) ^ (((a) >> 4) & 15))

// Module-scope device scratch (graph-capture safe, rewritten every call).
__device__ float2 g_Hh[I_DIM * NBIN];    // K_hat  [i][k], ~2.1 MB
__device__ float2 g_Kf[I_DIM * NBIN2];   // rfft_8192(K_pad) [i][m], ~4.2 MB

__device__ inline float2 cmul(float2 a, float2 b) {
    return make_float2(a.x * b.x - a.y * b.y, a.x * b.y + a.y * b.x);
}

// ---------------------------------------------------------------------------
// Radix-2 Stockham DIF forward FFT core, length NN = 2^NSTAGE, natural order
// in and out. 256 threads. Data in src; ping-pongs; on return `src` points at
// the result buffer. Verified index math: butterfly u reads x[u], x[u+NN/2],
// writes y[2u-q], y[2u-q+s] with q = u&(s-1), twiddle e^{-j*2*pi*(u-q)/NN}.
// ---------------------------------------------------------------------------
template <int NN, int NSTAGE>
__device__ inline void fft_core(float2*& src, float2*& dst, int tid) {
    const float cang = (float)(-6.283185307179586 / (double)NN);
    const int HALF = NN / 2;
    const int ITER = HALF / 256;
    for (int ls = 0; ls < NSTAGE; ++ls) {
        const int s = 1 << ls;
#pragma unroll
        for (int r = 0; r < ITER; ++r) {
            int u = tid + (r << 8);
            int q = u & (s - 1);
            float2 a = src[SZ(u)];
            float2 b = src[SZ(u + HALF)];
            float sn, cs;
            __sincosf(cang * (float)(u - q), &sn, &cs);
            float2 sum = make_float2(a.x + b.x, a.y + b.y);
            float2 dif = make_float2(a.x - b.x, a.y - b.y);
            float2 tw  = make_float2(dif.x * cs - dif.y * sn,
                                     dif.x * sn + dif.y * cs);
            int w = 2 * u - q;
            dst[SZ(w)]     = sum;
            dst[SZ(w + s)] = tw;
        }
        __syncthreads();
        float2* t = src; src = dst; dst = t;
    }
}

// ---------------------------------------------------------------------------
// Kernel 1: K_hat[i,k] (unchanged from round 2 — verified correct)
// ---------------------------------------------------------------------------
__global__ void khat_kernel(const float* __restrict__ Bm,
                            const float* __restrict__ Cm,
                            const float* __restrict__ Lm,
                            const float* __restrict__ Pm,
                            const float* __restrict__ Qm) {
    int k = blockIdx.x * blockDim.x + threadIdx.x;
    int i = blockIdx.y;
    if (k >= NBIN) return;

    float theta = (float)(6.283185307179586 / (double)SEQ) * (float)k;
    float sn, cs;
    sincosf(theta, &sn, &cs);

    float tr = 1.0f - cs, ti = -sn;
    float br = 1.0f + cs, bi = sn;
    float den = br * br + bi * bi;
    float idn = 1.0f / den;
    float gr = 20.0f * (tr * br + ti * bi) * idn;
    float gi = 20.0f * (ti * br - tr * bi) * idn;
    float cr = 2.0f * br * idn;
    float ci = -2.0f * bi * idn;

    const float* Brow = Bm + i * H_DIM;
    const float* Crow = Cm + i * H_DIM;
    const float* Lrow = Lm + i * H_DIM;
    const float* Prow = Pm + i * H_DIM;
    const float* Qrow = Qm + i * H_DIM;

    float k00r = 0.f, k00i = 0.f, k01r = 0.f, k01i = 0.f;
    float k10r = 0.f, k10i = 0.f, k11r = 0.f, k11i = 0.f;

#pragma unroll 8
    for (int h = 0; h < H_DIM; ++h) {
        float lam = Lrow[h];
        float dr = gr - lam;
        float di = gi;
        float im = 1.0f / (dr * dr + di * di);
        float ivr = dr * im;
        float ivi = -di * im;
        float bv = Brow[h], cv = Crow[h], pv = Prow[h], qv = Qrow[h];
        float cb = cv * bv;
        float cp = cv * pv;
        float qb = qv * bv;
        float qp = qv * pv;
        k00r += cb * ivr; k00i += cb * ivi;
        k01r += cp * ivr; k01i += cp * ivi;
        k10r += qb * ivr; k10i += qb * ivi;
        k11r += qp * ivr; k11i += qp * ivi;
    }

    float t1r = 1.0f + k11r, t1i = k11i;
    float t2r = k01r * t1r - k01i * t1i;
    float t2i = k01r * t1i + k01i * t1r;
    float t3r = t2r * k10r - t2i * k10i;
    float t3i = t2r * k10i + t2i * k10r;
    float nr = k00r - t3r, ni = k00i - t3i;
    float Hr = cr * nr - ci * ni;
    float Hi = cr * ni + ci * nr;
    g_Hh[(size_t)i * NBIN + k] = make_float2(Hr, Hi);
}

// ---------------------------------------------------------------------------
// Kernel 2: K-prep. Per channel i:
//   K = irfft_4096(K_hat)  (via half-size pack -> cfft_2048, conj trick)
//   Kf = rfft_8192(K_pad)  (even/odd pack -> cfft_4096 -> untwist)
// Never materializes K: icfft output pairs ARE the forward pack.
// ---------------------------------------------------------------------------
__global__ __launch_bounds__(256) void kprep_kernel() {
    __shared__ float2 lds[2][4096];
    const int tid = threadIdx.x;
    const int i = blockIdx.x;
    const float2* Hrow = g_Hh + (size_t)i * NBIN;

    // inverse-rfft half-size pack: Zk[m] = E[m] + j*O[m], store conj (icfft
    // via forward core).  E = (H[m]+conj(H[2048-m]))/2,
    // O = e^{+j*pi*m/2048} * (H[m]-conj(H[2048-m]))/2.
#pragma unroll
    for (int r = 0; r < 8; ++r) {
        int m = tid + (r << 8);          // m < 2048
        float2 Hm = Hrow[m];
        float2 Hc = Hrow[2048 - m];
        float pr = Hm.x + Hc.x, pi2 = Hm.y - Hc.y;   // Hm + conj(Hc)
        float dr = Hm.x - Hc.x, di = Hm.y + Hc.y;    // Hm - conj(Hc)
        float sn, cs;
        __sincosf((float)(3.141592653589793 / 2048.0) * (float)m, &sn, &cs);
        float Or = 0.5f * (cs * dr - sn * di);
        float Oi = 0.5f * (sn * dr + cs * di);
        lds[0][SZ(m)] = make_float2(0.5f * pr - Oi, -(0.5f * pi2 + Or));
    }
    __syncthreads();

    float2* src = lds[0];
    float2* dst = lds[1];
    fft_core<2048, 11>(src, dst, tid);   // result in src

    // v[n] = K[2n] + j*K[2n+1] = conj(out[n])/2048 for n<2048; zero above.
    float2* vbuf = dst;                   // the other buffer
    const float s1 = 1.0f / 2048.0f;
#pragma unroll
    for (int r = 0; r < 8; ++r) {
        int n = tid + (r << 8);
        float2 o = src[SZ(n)];
        vbuf[SZ(n)]        = make_float2(o.x * s1, -o.y * s1);
        vbuf[SZ(n + 2048)] = make_float2(0.f, 0.f);
    }
    __syncthreads();

    float2* s2 = vbuf;
    float2* d2 = src;
    fft_core<4096, 12>(s2, d2, tid);     // result in s2

    // untwist: Kf[m] = (Zv[m]+conj(Zv[4096-m]))/2
    //                - (j/2) e^{-j*pi*m/4096} (Zv[m]-conj(Zv[4096-m]))
    float2* Kfrow = g_Kf + (size_t)i * NBIN2;
#pragma unroll
    for (int r = 0; r < 17; ++r) {
        int m = tid + (r << 8);
        if (m <= 4096) {
            float2 Zq = s2[SZ(m & 4095)];
            float2 Zr = s2[SZ((4096 - m) & 4095)];
            float sn, cs;
            __sincosf((float)(-3.141592653589793 / 4096.0) * (float)m, &sn, &cs);
            float pr = Zq.x + Zr.x, pi2 = Zq.y - Zr.y;
            float dr = Zq.x - Zr.x, di = Zq.y + Zr.y;
            float jt_r = -sn * dr - cs * di;   // (j*t)*(dr,di), t=(cs,sn)
            float jt_i =  cs * dr - sn * di;
            Kfrow[m] = make_float2(0.5f * (pr - jt_r), 0.5f * (pi2 - jt_i));
        }
    }
}

// ---------------------------------------------------------------------------
// Kernel 3: FFT convolution, one block per (b,i).
//   z = pack(x row, zero-padded), Zx = cfft_4096(z)
//   combine: untwist -> *Kf -> retwist (uniform pair formula, m in [0,4096))
//   zy = icfft_4096 (conj trick), y = unpack(first 2048 complex)
// b = blockIdx&7: all 128 channel-blocks of one batch land on one XCD's L2.
// ---------------------------------------------------------------------------
__global__ __launch_bounds__(256) void fftconv_kernel(const float* __restrict__ x,
                                                      float* __restrict__ y) {
    __shared__ float2 lds[2][4096];
    const int tid = threadIdx.x;
    const int b = blockIdx.x & 7;
    const int i = blockIdx.x >> 3;

    const float* xb = x + (size_t)b * SEQ * I_DIM + i;
#pragma unroll
    for (int r = 0; r < 8; ++r) {
        int n = tid + (r << 8);          // n < 2048
        float re = xb[(size_t)(2 * n) * I_DIM];
        float im = xb[(size_t)(2 * n + 1) * I_DIM];
        lds[0][SZ(n)]        = make_float2(re, im);
        lds[0][SZ(n + 2048)] = make_float2(0.f, 0.f);
    }
    __syncthreads();

    float2* src = lds[0];
    float2* dst = lds[1];
    fft_core<4096, 12>(src, dst, tid);   // Zx in src

    const float2* Kfrow = g_Kf + (size_t)i * NBIN2;
#pragma unroll
    for (int r = 0; r < 16; ++r) {
        int m = tid + (r << 8);          // m < 4096
        float2 Zq = src[SZ(m)];
        float2 Zr = src[SZ((4096 - m) & 4095)];
        float sn, cs;
        __sincosf((float)(-3.141592653589793 / 4096.0) * (float)m, &sn, &cs);
        // t1 = (cs,sn) = e^{-j*pi*m/4096}
        float pr = Zq.x + Zr.x, pi2 = Zq.y - Zr.y;   // Zq + conj(Zr)
        float dr = Zq.x - Zr.x, di = Zq.y + Zr.y;    // Zq - conj(Zr)
        float jt_r = -sn * dr - cs * di;             // (j*t1)*(dr,di)
        float jt_i =  cs * dr - sn * di;
        float2 Xm  = make_float2(0.5f * (pr - jt_r),  0.5f * ( pi2 - jt_i));
        // X[4096-m]: t2 = -conj(t1); (j*t2)*(Zr-conj(Zq)) = (-jt_r, jt_i)
        float2 Xm2 = make_float2(0.5f * (pr + jt_r),  0.5f * (-pi2 - jt_i));

        float2 Ym  = cmul(Xm,  Kfrow[m]);
        float2 Ym2 = cmul(Xm2, Kfrow[4096 - m]);

        // Zy[m] = (Ym + conj(Ym2))/2 + j*conj(t1)*(Ym - conj(Ym2))/2
        float qr = Ym.x + Ym2.x, qi = Ym.y - Ym2.y;
        float er = Ym.x - Ym2.x, ei = Ym.y + Ym2.y;
        float gr2 = sn * er - cs * ei;   // (j*conj(t1)) = (sn, cs)
        float gi2 = sn * ei + cs * er;
        // store conj(Zy) for the conj-trick inverse
        dst[SZ(m)] = make_float2(0.5f * (qr + gr2), -0.5f * (qi + gi2));
    }
    __syncthreads();

    float2* s2  = dst;
    float2* d2b = src;
    fft_core<4096, 12>(s2, d2b, tid);    // result in s2

    const float inv = 1.0f / 4096.0f;
    float* yb = y + (size_t)b * SEQ * I_DIM + i;
#pragma unroll
    for (int r = 0; r < 8; ++r) {
        int n = tid + (r << 8);          // n < 2048
        float2 v = s2[SZ(n)];
        yb[(size_t)(2 * n) * I_DIM]     = v.x * inv;
        yb[(size_t)(2 * n + 1) * I_DIM] = -v.y * inv;
    }
}

// ---------------------------------------------------------------------------
extern "C" void kernel_launch(void* const* d_in, const int* in_sizes, int n_in,
                              void* d_out, int out_size, void* d_ws, size_t ws_size,
                              hipStream_t stream) {
    const float* x  = (const float*)d_in[0];
    const float* Bm = (const float*)d_in[1];
    const float* Cm = (const float*)d_in[2];
    const float* Lm = (const float*)d_in[3];
    const float* Pm = (const float*)d_in[4];
    const float* Qm = (const float*)d_in[5];
    float* out = (float*)d_out;

    khat_kernel<<<dim3((NBIN + 255) / 256, I_DIM), 256, 0, stream>>>(Bm, Cm, Lm, Pm, Qm);
    kprep_kernel<<<I_DIM, 256, 0, stream>>>();
    fftconv_kernel<<<BATCH * I_DIM, 256, 0, stream>>>(x, out);
}